// Round 8
// baseline (602.304 us; speedup 1.0000x reference)
//
#include <hip/hip_runtime.h>
#include <math.h>

#define Bq 64
#define Tq 1024
#define Nq 128

typedef __attribute__((ext_vector_type(2))) _Float16 h2;

#if defined(__has_builtin)
#  if __has_builtin(__builtin_amdgcn_fdot2)
#    define HAVE_FDOT2 1
#  endif
#endif

__device__ __forceinline__ float dot2acc(h2 a, h2 b, float c) {
#ifdef HAVE_FDOT2
    return __builtin_amdgcn_fdot2(a, b, c, false);
#else
    return c + (float)a.x * (float)b.x + (float)a.y * (float)b.y;
#endif
}

union Q16 { int4 v; h2 p[4]; };

// ---------------------------------------------------------------------------
// Prep: pack E = exp(transitions) as f16 pairs, column-major:
//   ws_h2[n*64 + j] = ( exp(T[2j][n]), exp(T[2j+1][n]) )
// Identical bits to R3/R7 (proven absmax 0.0).
// ---------------------------------------------------------------------------
__global__ __launch_bounds__(256)
void crf_prep_kernel(const float* __restrict__ transitions, h2* __restrict__ ws) {
    const int P = blockIdx.x * 256 + threadIdx.x;   // 0..8191
    const int n = P >> 6;
    const int j = P & 63;
    h2 w;
    w.x = (_Float16)__expf(transitions[(2 * j)     * Nq + n]);
    w.y = (_Float16)__expf(transitions[(2 * j + 1) * Nq + n]);
    ws[P] = w;
}

// ---------------------------------------------------------------------------
// Blocks 0..63: forward chain b — ONE wave, lane owns states L and L+64.
// E columns are staged in LDS (padded [128][17] int4 rows, stride 272 B:
// bank-group = 4*(L+q) mod 32 -> exactly 8 accesses/bank per b128 = HW floor,
// zero conflicts, addresses are base + immediate offset). Read fresh each
// step: 32 ds_read_b128 (E) + 16 broadcast ds_read_b128 (p) + 128 v_dot2.
// Numerics identical to R3/R7: log-domain, M_next = M + log(max4 p) + 7,
// p = min(exp(alpha - M), 60000) stored f16.
// Blocks 64..127: gold-path score for chain (blockIdx-64).
// ---------------------------------------------------------------------------
__global__ __launch_bounds__(64, 1)
void crf_main_kernel(const float* __restrict__ emissions,
                     const int* __restrict__ token_sizes,
                     const int* __restrict__ targets,
                     const float* __restrict__ transitions,
                     const float* __restrict__ head,
                     const float* __restrict__ last,
                     const h2* __restrict__ Ews,
                     float* __restrict__ out) {
    const int L = threadIdx.x;

    if (blockIdx.x >= Bq) {
        // ---------------- score path ----------------
        const int b = blockIdx.x - Bq;
        const int tsz = token_sizes[b];
        const int* tg = targets + b * Tq;
        const float* em = emissions + (size_t)b * Tq * Nq;
        float sc = 0.f;
        for (int t = L; t < tsz; t += 64) {
            int cur = tg[t];
            sc += em[(size_t)t * Nq + cur];
            if (t >= 1) sc += transitions[tg[t - 1] * Nq + cur];
        }
        #pragma unroll
        for (int off = 32; off >= 1; off >>= 1)
            sc += __shfl_xor(sc, off, 64);
        if (L == 0) out[Bq + b] = sc + head[tg[0]] + last[tg[tsz - 1]];
        return;
    }

    // ---------------- forward path ----------------
    const int b = blockIdx.x;
    const int n0 = L;
    const int n1 = L + 64;

    __shared__ __align__(16) int4 E4[Nq][17];       // padded: stride 272 B
    __shared__ __align__(16) _Float16 p_lds[Nq];

    // stage E columns n0, n1 into LDS (one-time; ws is L2-resident)
    {
        const int4* W4 = (const int4*)Ews;
        #pragma unroll
        for (int q = 0; q < 16; ++q) E4[n0][q] = W4[n0 * 16 + q];
        #pragma unroll
        for (int q = 0; q < 16; ++q) E4[n1][q] = W4[n1 * 16 + q];
    }

    const float* em = emissions + (size_t)b * Tq * Nq;
    const int tsz = token_sizes[b];   // in [T/2, T]

    float aA = head[n0] + em[n0];
    float aB = head[n1] + em[n1];

    float M;
    {
        float w = fmaxf(aA, aB);
        #pragma unroll
        for (int off = 32; off >= 1; off >>= 1)
            w = fmaxf(w, __shfl_xor(w, off, 64));
        M = w;
    }

    // emission prefetch depth 2 (tsz >= 512)
    float fA0 = em[1 * Nq + n0], fB0 = em[1 * Nq + n1];
    float fA1 = em[2 * Nq + n0], fB1 = em[2 * Nq + n1];

    const int4* Erow0 = &E4[n0][0];
    const int4* Erow1 = &E4[n1][0];

    __syncthreads();   // staging complete (single wave: cheap fence)

    for (int t = 1; t < tsz; ++t) {
        float pA = fminf(__expf(aA - M), 60000.0f);
        float pB = fminf(__expf(aB - M), 60000.0f);
        p_lds[n0] = (_Float16)pA;
        p_lds[n1] = (_Float16)pB;

        const int tn = min(t + 2, tsz - 1);
        float fA2 = em[(size_t)tn * Nq + n0], fB2 = em[(size_t)tn * Nq + n1];

        __syncthreads();   // orders p stores before reads (full fence)

        const int4* p4 = (const int4*)p_lds;
        Q16 U[16];
        #pragma unroll
        for (int q = 0; q < 16; ++q) U[q].v = p4[q];   // broadcast reads
        asm volatile("" ::: "memory");  // next iter's stores can't hoist above

        // sampled max of p[0..3] — identical to R3/R7
        float pm = fmaxf(fmaxf((float)U[0].p[0].x, (float)U[0].p[0].y),
                         fmaxf((float)U[0].p[1].x, (float)U[0].p[1].y));
        pm = fmaxf(pm, 1e-6f);

        float sA[4] = {0.f, 0.f, 0.f, 0.f};
        float sB[4] = {0.f, 0.f, 0.f, 0.f};
        #pragma unroll
        for (int q = 0; q < 16; ++q) {
            Q16 ea, eb;
            ea.v = Erow0[q];       // ds_read_b128, base + offset:q*16
            eb.v = Erow1[q];
            #pragma unroll
            for (int r = 0; r < 4; ++r) {   // j = 4q + r  (R3/R7 order)
                sA[r] = dot2acc(U[q].p[r], ea.p[r], sA[r]);
                sB[r] = dot2acc(U[q].p[r], eb.p[r], sB[r]);
            }
        }
        float ssA = (sA[0] + sA[1]) + (sA[2] + sA[3]);
        float ssB = (sB[0] + sB[1]) + (sB[2] + sB[3]);

        aA = M + __logf(ssA) + fA0;
        aB = M + __logf(ssB) + fB0;
        M += __logf(pm) + 7.0f;

        fA0 = fA1; fB0 = fB1;
        fA1 = fA2; fB1 = fB2;
    }

    // ---- log_partitions[b] = lse over 128 states (2 per lane) ----
    {
        float vA = aA + last[n0];
        float vB = aB + last[n1];
        float w = fmaxf(vA, vB);
        #pragma unroll
        for (int off = 32; off >= 1; off >>= 1)
            w = fmaxf(w, __shfl_xor(w, off, 64));
        float sum = __expf(vA - w) + __expf(vB - w);
        #pragma unroll
        for (int off = 32; off >= 1; off >>= 1)
            sum += __shfl_xor(sum, off, 64);
        if (L == 0) out[b] = w + __logf(sum);
    }
}

extern "C" void kernel_launch(void* const* d_in, const int* in_sizes, int n_in,
                              void* d_out, int out_size, void* d_ws, size_t ws_size,
                              hipStream_t stream) {
    const float* emissions   = (const float*)d_in[0];
    const int*   token_sizes = (const int*)d_in[1];
    const int*   targets     = (const int*)d_in[2];
    const float* transitions = (const float*)d_in[3];  // (1,1,128,128)
    const float* head        = (const float*)d_in[4];  // (1,1,128)
    const float* last        = (const float*)d_in[5];  // (1,1,128)
    float* out = (float*)d_out;                        // (2,64,1) flat
    h2* Ews = (h2*)d_ws;                               // 8192 h2 = 32 KB

    crf_prep_kernel<<<32, 256, 0, stream>>>(transitions, Ews);
    crf_main_kernel<<<2 * Bq, 64, 0, stream>>>(emissions, token_sizes, targets,
                                               transitions, head, last, Ews, out);
}

// Round 9
// 530.542 us; speedup vs baseline: 1.1353x; 1.1353x over previous
//
#include <hip/hip_runtime.h>
#include <math.h>

#define Bq 64
#define Tq 1024
#define Nq 128

typedef __attribute__((ext_vector_type(2))) _Float16 h2;

#if defined(__has_builtin)
#  if __has_builtin(__builtin_amdgcn_fdot2)
#    define HAVE_FDOT2 1
#  endif
#endif

__device__ __forceinline__ float dot2acc(h2 a, h2 b, float c) {
#ifdef HAVE_FDOT2
    return __builtin_amdgcn_fdot2(a, b, c, false);
#else
    return c + (float)a.x * (float)b.x + (float)a.y * (float)b.y;
#endif
}

union Q16 { int4 v; h2 p[4]; };

// ---------------------------------------------------------------------------
// One forward step. 4-wave matvec split:
//   lane (w,l): quad q=l>>2 owns states n0=16w+q, n1=n0+64; h=l&3 owns
//   m-quarter [32h, 32h+32). Per lane: 4 broadcast ds_read_b128 of p,
//   32 v_dot2_f32_f16, quad-combine via 2 shfl_xor. One barrier per step,
//   double-buffered p (rb -> wb). Numerics identical to the proven R3:
//   M_next = M + log(max4 sampled p) + 7;  p = min(exp(alpha-M_next), 60000).
// ---------------------------------------------------------------------------
__device__ __forceinline__ void fwd_step(
    int t, int tsz, int h, const float* __restrict__ em_c, int n0, int n1,
    const _Float16* __restrict__ rb, _Float16* __restrict__ wb,
    const h2 (&eA)[16], const h2 (&eB)[16],
    float& emitA, float& emitB, float& aA, float& aB, float& M)
{
    __syncthreads();                       // p(t) fully written in rb

    const int4* p4 = (const int4*)(rb + (h << 5));   // this lane's m-quarter
    Q16 U[4];
    #pragma unroll
    for (int u = 0; u < 4; ++u) U[u].v = p4[u];      // broadcast reads
    asm volatile("" ::: "memory");         // keep wb stores below the reads

    // sampled max of p[0..3] (same sample as R3), shared quad-wide
    float pmv = 0.f;
    if (h == 0) {
        pmv = fmaxf(fmaxf((float)U[0].p[0].x, (float)U[0].p[0].y),
                    fmaxf((float)U[0].p[1].x, (float)U[0].p[1].y));
    }
    pmv = fmaxf(pmv, __shfl_xor(pmv, 1, 64));
    pmv = fmaxf(pmv, __shfl_xor(pmv, 2, 64));
    const float pm = fmaxf(pmv, 1e-6f);

    float sA[4] = {0.f, 0.f, 0.f, 0.f};
    float sB[4] = {0.f, 0.f, 0.f, 0.f};
    #pragma unroll
    for (int k = 0; k < 16; ++k) {         // static indices after unroll
        h2 pk = U[k >> 2].p[k & 3];
        sA[k & 3] = dot2acc(pk, eA[k], sA[k & 3]);
        sB[k & 3] = dot2acc(pk, eB[k], sB[k & 3]);
    }
    float ssA = (sA[0] + sA[1]) + (sA[2] + sA[3]);
    float ssB = (sB[0] + sB[1]) + (sB[2] + sB[3]);
    ssA += __shfl_xor(ssA, 1, 64);  ssA += __shfl_xor(ssA, 2, 64);
    ssB += __shfl_xor(ssB, 1, 64);  ssB += __shfl_xor(ssB, 2, 64);

    const float Mn = M + __logf(pm) + 7.0f;
    aA = M + __logf(ssA) + emitA;
    aB = M + __logf(ssB) + emitB;

    // refill emission regs for step t+4 (used 4 unrolled bodies later)
    {
        const size_t idx = (size_t)min(t + 4, tsz - 1) * Nq;
        emitA = em_c[idx + n0];
        emitB = em_c[idx + n1];
    }

    const float pA = fminf(__expf(aA - Mn), 60000.0f);
    const float pB = fminf(__expf(aB - Mn), 60000.0f);
    if (h == 0) wb[n0] = (_Float16)pA;
    if (h == 1) wb[n1] = (_Float16)pB;
    M = Mn;
}

// ---------------------------------------------------------------------------
// Blocks 0..63: forward chain b (256 threads, 4 waves).
// Blocks 64..127: gold-path score for chain (blockIdx-64).
// ---------------------------------------------------------------------------
__global__ __launch_bounds__(256, 1)
void crf_kernel(const float* __restrict__ emissions,
                const int* __restrict__ token_sizes,
                const int* __restrict__ targets,
                const float* __restrict__ transitions,
                const float* __restrict__ head,
                const float* __restrict__ last,
                float* __restrict__ out) {
    const int tid = threadIdx.x;

    if (blockIdx.x >= Bq) {
        // ---------------- score path ----------------
        const int b = blockIdx.x - Bq;
        const int tsz = token_sizes[b];
        const int* tg = targets + b * Tq;
        const float* em = emissions + (size_t)b * Tq * Nq;
        float sc = 0.f;
        for (int t = tid; t < tsz; t += 256) {
            int cur = tg[t];
            sc += em[(size_t)t * Nq + cur];
            if (t >= 1) sc += transitions[tg[t - 1] * Nq + cur];
        }
        #pragma unroll
        for (int off = 32; off >= 1; off >>= 1)
            sc += __shfl_xor(sc, off, 64);
        __shared__ float wsum[4];
        if ((tid & 63) == 0) wsum[tid >> 6] = sc;
        __syncthreads();
        if (tid == 0) {
            float tot = wsum[0] + wsum[1] + wsum[2] + wsum[3];
            out[Bq + b] = tot + head[tg[0]] + last[tg[tsz - 1]];
        }
        return;
    }

    // ---------------- forward path ----------------
    const int w = tid >> 6;          // wave 0..3
    const int l = tid & 63;
    const int q = l >> 2;            // quad 0..15
    const int h = l & 3;             // m-quarter
    const int n0 = (w << 4) + q;     // owned states
    const int n1 = n0 + 64;
    const int b = blockIdx.x;

    __shared__ __align__(16) _Float16 pbuf[2][Nq];
    __shared__ float redA[4], redB[4];

    // E fragments: eA[k] = (exp(T[32h+2k][n0]), exp(T[32h+2k+1][n0]))
    h2 eA[16], eB[16];
    #pragma unroll
    for (int k = 0; k < 16; ++k) {
        const int m = 32 * h + 2 * k;
        h2 va, vb;
        va.x = (_Float16)__expf(transitions[(m)     * Nq + n0]);
        va.y = (_Float16)__expf(transitions[(m + 1) * Nq + n0]);
        vb.x = (_Float16)__expf(transitions[(m)     * Nq + n1]);
        vb.y = (_Float16)__expf(transitions[(m + 1) * Nq + n1]);
        eA[k] = va;
        eB[k] = vb;
    }
    #pragma unroll
    for (int k = 0; k < 16; ++k) asm volatile("" : "+v"(eA[k]), "+v"(eB[k]));

    const float* em = emissions + (size_t)b * Tq * Nq;
    const int tsz = token_sizes[b];  // in [T/2, T], uniform per block

    float aA = head[n0] + em[n0];
    float aB = head[n1] + em[n1];

    // M0 = true max of alpha0 (one-time block reduce)
    float M;
    {
        float mv = fmaxf(aA, aB);
        #pragma unroll
        for (int off = 32; off >= 1; off >>= 1)
            mv = fmaxf(mv, __shfl_xor(mv, off, 64));
        if (l == 0) redA[w] = mv;
        __syncthreads();
        M = fmaxf(fmaxf(redA[0], redA[1]), fmaxf(redA[2], redA[3]));
    }

    // initial p(1) -> buffer 0
    if (h == 0) pbuf[0][n0] = (_Float16)__expf(aA - M);
    if (h == 1) pbuf[0][n1] = (_Float16)__expf(aB - M);

    // emission prefetch: emits for t = 1..4 (tsz >= 512, indices valid)
    float emA0 = em[1 * Nq + n0], emB0 = em[1 * Nq + n1];
    float emA1 = em[2 * Nq + n0], emB1 = em[2 * Nq + n1];
    float emA2 = em[3 * Nq + n0], emB2 = em[3 * Nq + n1];
    float emA3 = em[4 * Nq + n0], emB3 = em[4 * Nq + n1];

    _Float16* b0 = &pbuf[0][0];
    _Float16* b1 = &pbuf[1][0];

    int t = 1;
    for (; t + 3 <= tsz - 1; t += 4) {
        fwd_step(t,     tsz, h, em, n0, n1, b0, b1, eA, eB, emA0, emB0, aA, aB, M);
        fwd_step(t + 1, tsz, h, em, n0, n1, b1, b0, eA, eB, emA1, emB1, aA, aB, M);
        fwd_step(t + 2, tsz, h, em, n0, n1, b0, b1, eA, eB, emA2, emB2, aA, aB, M);
        fwd_step(t + 3, tsz, h, em, n0, n1, b1, b0, eA, eB, emA3, emB3, aA, aB, M);
    }
    // remainder (<= 3 steps; tsz uniform per block so barriers stay uniform)
    if (t <= tsz - 1) {
        fwd_step(t, tsz, h, em, n0, n1, b0, b1, eA, eB, emA0, emB0, aA, aB, M);
        ++t;
        if (t <= tsz - 1) {
            fwd_step(t, tsz, h, em, n0, n1, b1, b0, eA, eB, emA1, emB1, aA, aB, M);
            ++t;
            if (t <= tsz - 1) {
                fwd_step(t, tsz, h, em, n0, n1, b0, b1, eA, eB, emA2, emB2, aA, aB, M);
            }
        }
    }

    // ---- log_partitions[b] = lse over 128 states ----
    {
        float vA = aA + last[n0];
        float vB = aB + last[n1];
        float mv = fmaxf(vA, vB);
        #pragma unroll
        for (int off = 32; off >= 1; off >>= 1)
            mv = fmaxf(mv, __shfl_xor(mv, off, 64));
        if (l == 0) redA[w] = mv;
        __syncthreads();
        const float mx = fmaxf(fmaxf(redA[0], redA[1]), fmaxf(redA[2], redA[3]));

        float su = (h == 0) ? (__expf(vA - mx) + __expf(vB - mx)) : 0.f;
        #pragma unroll
        for (int off = 32; off >= 1; off >>= 1)
            su += __shfl_xor(su, off, 64);
        if (l == 0) redB[w] = su;
        __syncthreads();
        if (tid == 0)
            out[b] = mx + __logf(((redB[0] + redB[1]) + (redB[2] + redB[3])));
    }
}

extern "C" void kernel_launch(void* const* d_in, const int* in_sizes, int n_in,
                              void* d_out, int out_size, void* d_ws, size_t ws_size,
                              hipStream_t stream) {
    const float* emissions   = (const float*)d_in[0];
    const int*   token_sizes = (const int*)d_in[1];
    const int*   targets     = (const int*)d_in[2];
    const float* transitions = (const float*)d_in[3];  // (1,1,128,128)
    const float* head        = (const float*)d_in[4];  // (1,1,128)
    const float* last        = (const float*)d_in[5];  // (1,1,128)
    float* out = (float*)d_out;                        // (2,64,1) flat

    crf_kernel<<<2 * Bq, 256, 0, stream>>>(emissions, token_sizes, targets,
                                           transitions, head, last, out);
}

// Round 10
// 329.374 us; speedup vs baseline: 1.8286x; 1.6108x over previous
//
#include <hip/hip_runtime.h>
#include <math.h>

#define Bq 64
#define Tq 1024
#define Nq 128

typedef __attribute__((ext_vector_type(2))) _Float16 h2;

#if defined(__has_builtin)
#  if __has_builtin(__builtin_amdgcn_fdot2)
#    define HAVE_FDOT2 1
#  endif
#  if __has_builtin(__builtin_amdgcn_rcpf)
#    define HAVE_RCPF 1
#  endif
#endif

__device__ __forceinline__ float dot2acc(h2 a, h2 b, float c) {
#ifdef HAVE_FDOT2
    return __builtin_amdgcn_fdot2(a, b, c, false);
#else
    return c + (float)a.x * (float)b.x + (float)a.y * (float)b.y;
#endif
}

__device__ __forceinline__ float fastrcp(float x) {
#ifdef HAVE_RCPF
    return __builtin_amdgcn_rcpf(x);
#else
    return 1.0f / x;
#endif
}

union Q16 { int4 v; h2 p[4]; };

#define EXP_NEG7 9.118819655545162e-4f

// ---------------------------------------------------------------------------
// One forward step (transition into time t). rb holds p_{t-1}; writes p_t to wb.
// Transcendental-free critical path:
//   p_t[n] = min( (sum_m p_{t-1}[m] E[m][n]) * ee_t[n] * rcp(pm)*e^-7, 60000 )
// where ee_t = exp(emit_t) comes from a 5-deep prefetch pipeline and pm is the
// R3-proven sampled max of p[0..3] (uniform across lanes via broadcast reads).
// Side chain (off critical path): Mcur += log(pm) + 7.
// ---------------------------------------------------------------------------
__device__ __forceinline__ void step_body(
    int t, int tsz, int n, const float* __restrict__ em_n,
    const _Float16* __restrict__ rb, _Float16* __restrict__ wb,
    const h2 (&e)[64],
    float& ee0, float& ee1, float& ee2, float& raw3, float& raw4,
    float& Mcur, float& plast)
{
    __syncthreads();                       // p_{t-1} fully written in rb

    const int4* p4 = (const int4*)rb;
    Q16 U[16];
    #pragma unroll
    for (int q = 0; q < 16; ++q) U[q].v = p4[q];     // broadcast reads
    asm volatile("" ::: "memory");         // keep wb store below the reads

    // sampled max of p[0..3] (R3 recipe), identical in every lane
    float pm = fmaxf(fmaxf((float)U[0].p[0].x, (float)U[0].p[0].y),
                     fmaxf((float)U[0].p[1].x, (float)U[0].p[1].y));
    pm = fmaxf(pm, 1e-6f);
    const float f = ee0 * (fastrcp(pm) * EXP_NEG7);  // ready before dot2s end

    // issue emission load for step t+5 (off path)
    const float raw5 = em_n[(size_t)min(t + 5, tsz - 1) * Nq];

    float s[4] = {0.f, 0.f, 0.f, 0.f};
    #pragma unroll
    for (int j = 0; j < 64; ++j)                     // static after unroll
        s[j & 3] = dot2acc(U[j >> 2].p[j & 3], e[j], s[j & 3]);
    const float ss = (s[0] + s[1]) + (s[2] + s[3]);

    const float pn = fminf(ss * f, 60000.0f);
    wb[n] = (_Float16)pn;
    plast = pn;

    // side chains (loop-carried only on themselves)
    Mcur += __logf(pm) + 7.0f;
    const float eeN = __expf(raw3);        // raw3 was loaded 3 steps ago
    ee0 = ee1; ee1 = ee2; ee2 = eeN;
    raw3 = raw4; raw4 = raw5;
}

// ---------------------------------------------------------------------------
// Blocks 0..63: forward chain b — 128 threads (2 waves), lane owns state n=tid.
//   E column n = 64 h2 VGPRs. One barrier + one 256 B LDS round-trip per step.
// Blocks 64..127: gold-path score for chain (blockIdx-64).
// ---------------------------------------------------------------------------
__global__ __launch_bounds__(128, 1)
void crf_kernel(const float* __restrict__ emissions,
                const int* __restrict__ token_sizes,
                const int* __restrict__ targets,
                const float* __restrict__ transitions,
                const float* __restrict__ head,
                const float* __restrict__ last,
                float* __restrict__ out) {
    const int tid = threadIdx.x;

    if (blockIdx.x >= Bq) {
        // ---------------- score path ----------------
        const int b = blockIdx.x - Bq;
        const int tsz = token_sizes[b];
        const int* tg = targets + b * Tq;
        const float* em = emissions + (size_t)b * Tq * Nq;
        float sc = 0.f;
        for (int t = tid; t < tsz; t += 128) {
            int cur = tg[t];
            sc += em[(size_t)t * Nq + cur];
            if (t >= 1) sc += transitions[tg[t - 1] * Nq + cur];
        }
        #pragma unroll
        for (int off = 32; off >= 1; off >>= 1)
            sc += __shfl_xor(sc, off, 64);
        __shared__ float wsum[2];
        if ((tid & 63) == 0) wsum[tid >> 6] = sc;
        __syncthreads();
        if (tid == 0)
            out[Bq + b] = wsum[0] + wsum[1] + head[tg[0]] + last[tg[tsz - 1]];
        return;
    }

    // ---------------- forward path ----------------
    const int n = tid;               // owned state
    const int wv = tid >> 6;
    const int l = tid & 63;
    const int b = blockIdx.x;
    const float* em_c = emissions + (size_t)b * Tq * Nq;
    const float* em_n = em_c + n;    // per-lane base: em_n[t*Nq] = emit_t[n]
    const int tsz = token_sizes[b];  // in [T/2, T]

    __shared__ __align__(16) _Float16 pbuf[2][Nq];
    __shared__ float redA[2], redB[2];

    // E column n: e[j] = (exp(T[2j][n]), exp(T[2j+1][n]))
    h2 e[64];
    #pragma unroll
    for (int j = 0; j < 64; ++j) {
        h2 v;
        v.x = (_Float16)__expf(transitions[(2 * j)     * Nq + n]);
        v.y = (_Float16)__expf(transitions[(2 * j + 1) * Nq + n]);
        e[j] = v;
    }
    #pragma unroll
    for (int j = 0; j < 64; ++j) asm volatile("" : "+v"(e[j]));

    // alpha0 and uniform M0 (one-time block reduce)
    const float a0 = head[n] + em_n[0];
    float Mcur;
    {
        float w = a0;
        #pragma unroll
        for (int off = 32; off >= 1; off >>= 1)
            w = fmaxf(w, __shfl_xor(w, off, 64));
        if (l == 0) redA[wv] = w;
        __syncthreads();
        Mcur = fmaxf(redA[0], redA[1]);
    }
    pbuf[0][n] = (_Float16)__expf(a0 - Mcur);   // p_0, in (0,1]

    // emission pipeline: ee for t=1,2,3 ; raw for t=4,5  (tsz >= 512)
    float ee0 = __expf(em_n[1 * Nq]);
    float ee1 = __expf(em_n[2 * Nq]);
    float ee2 = __expf(em_n[3 * Nq]);
    float raw3 = em_n[4 * Nq];
    float raw4 = em_n[5 * Nq];

    float plast = 0.f;
    _Float16* b0 = &pbuf[0][0];
    _Float16* b1 = &pbuf[1][0];

    // main loop: step t reads buf[(t-1)&1], writes buf[t&1]; start t=1
    int t = 1;
    for (; t + 3 <= tsz - 1; t += 4) {
        step_body(t,     tsz, n, em_n, b0, b1, e, ee0, ee1, ee2, raw3, raw4, Mcur, plast);
        step_body(t + 1, tsz, n, em_n, b1, b0, e, ee0, ee1, ee2, raw3, raw4, Mcur, plast);
        step_body(t + 2, tsz, n, em_n, b0, b1, e, ee0, ee1, ee2, raw3, raw4, Mcur, plast);
        step_body(t + 3, tsz, n, em_n, b1, b0, e, ee0, ee1, ee2, raw3, raw4, Mcur, plast);
    }
    // remainder (t ≡ 1 mod 4 here; tsz uniform per block -> uniform barriers)
    if (t <= tsz - 1) {
        step_body(t, tsz, n, em_n, b0, b1, e, ee0, ee1, ee2, raw3, raw4, Mcur, plast);
        ++t;
        if (t <= tsz - 1) {
            step_body(t, tsz, n, em_n, b1, b0, e, ee0, ee1, ee2, raw3, raw4, Mcur, plast);
            ++t;
            if (t <= tsz - 1)
                step_body(t, tsz, n, em_n, b0, b1, e, ee0, ee1, ee2, raw3, raw4, Mcur, plast);
        }
    }

    // ---- logZ = Mcur + log( sum_n p_final[n] * exp(last[n]) ) ----
    {
        float z = plast * __expf(last[n]);
        #pragma unroll
        for (int off = 32; off >= 1; off >>= 1)
            z += __shfl_xor(z, off, 64);
        if (l == 0) redB[wv] = z;
        __syncthreads();
        if (tid == 0) out[b] = Mcur + __logf(redB[0] + redB[1]);
    }
}

extern "C" void kernel_launch(void* const* d_in, const int* in_sizes, int n_in,
                              void* d_out, int out_size, void* d_ws, size_t ws_size,
                              hipStream_t stream) {
    const float* emissions   = (const float*)d_in[0];
    const int*   token_sizes = (const int*)d_in[1];
    const int*   targets     = (const int*)d_in[2];
    const float* transitions = (const float*)d_in[3];  // (1,1,128,128)
    const float* head        = (const float*)d_in[4];  // (1,1,128)
    const float* last        = (const float*)d_in[5];  // (1,1,128)
    float* out = (float*)d_out;                        // (2,64,1) flat

    crf_kernel<<<2 * Bq, 128, 0, stream>>>(emissions, token_sizes, targets,
                                           transitions, head, last, out);
}